// Round 1
// baseline (661.940 us; speedup 1.0000x reference)
//
#include <hip/hip_runtime.h>
#include <math.h>

#define N_BINS 15

typedef float vfloat4 __attribute__((ext_vector_type(4)));

// ---- helpers ---------------------------------------------------------------

// Load one row (C floats, C%4==0, C<=1024) into 4 float4 regs per lane.
// Out-of-range lanes clamp to the last float4 (same cacheline, no divergence);
// the invalid groups are masked to -INF at compute time.
__device__ __forceinline__ void load_row(const float* __restrict__ logits,
                                         size_t row, int C, int lane, int n4,
                                         vfloat4 buf[4])
{
    const vfloat4* __restrict__ rowp = (const vfloat4*)(logits + row * (size_t)C);
    #pragma unroll
    for (int g = 0; g < 4; ++g) {
        const int j  = lane + 64 * g;
        const int jc = (j < n4) ? j : (n4 - 1);
        buf[g] = rowp[jc];
    }
}

__device__ __forceinline__ void compute_row(const vfloat4 buf[4], int lane, int n4,
                                            const int* __restrict__ labels,
                                            float* __restrict__ seg_buf, int row)
{
    float v[16];
    #pragma unroll
    for (int g = 0; g < 4; ++g) {
        const bool valid = (lane + 64 * g) < n4;
        v[4*g+0] = valid ? buf[g].x : -INFINITY;
        v[4*g+1] = valid ? buf[g].y : -INFINITY;
        v[4*g+2] = valid ? buf[g].z : -INFINITY;
        v[4*g+3] = valid ? buf[g].w : -INFINITY;
    }

    // Lane-local max (tree) + first-occurrence index of the lane-local max.
    float m = v[0];
    #pragma unroll
    for (int k = 1; k < 16; ++k) m = fmaxf(m, v[k]);

    int cand = 0x7fffffff;
    #pragma unroll
    for (int g = 0; g < 4; ++g) {
        #pragma unroll
        for (int e = 0; e < 4; ++e) {
            const int idx = 4 * (lane + 64 * g) + e;
            cand = (v[4*g+e] == m && idx < cand) ? idx : cand;
        }
    }

    // Fused (max, argmax) butterfly: 6 rounds instead of 6+6.
    // Hierarchical min-index-among-maxima == global first-occurrence argmax.
    #pragma unroll
    for (int off = 32; off >= 1; off >>= 1) {
        const float mo = __shfl_xor(m, off, 64);
        const int   co = __shfl_xor(cand, off, 64);
        const bool take = (mo > m);
        const bool tie  = (mo == m);
        const int  cmin = (co < cand) ? co : cand;
        cand = take ? co : (tie ? cmin : cand);
        m    = fmaxf(m, mo);
    }

    // Softmax denominator: bit-identical order to the previous kernel
    // (global m subtraction, k=0..15 lane order, 6-round add butterfly).
    float s = 0.0f;
    #pragma unroll
    for (int k = 0; k < 16; ++k) s += __expf(v[k] - m);
    #pragma unroll
    for (int off = 32; off >= 1; off >>= 1) s += __shfl_xor(s, off, 64);

    if (lane == 0) {
        const float conf = 1.0f / s;               // exp(m-m)/sum
        int bin = (int)ceilf(conf * (float)N_BINS) - 1;
        bin = bin < 0 ? 0 : (bin > N_BINS - 1 ? N_BINS - 1 : bin);
        const int label = labels[row];
        const float acc = (cand == label) ? 1.0f : 0.0f;
        atomicAdd(&seg_buf[label * N_BINS + bin], conf - acc);
    }
}

// ---- main kernel: grid-stride rows, software-pipelined prefetch ------------
// 2048 blocks x 4 waves = 8192 wave-slots; each wave walks rows w, w+W, ...
// While reducing row i (two shuffle chains, 16 exps), row i+1's 4 KB is in
// flight -> HBM latency hidden, kernel runs at read bandwidth.
__global__ __launch_bounds__(256) void ecce_rows_kernel(
    const float* __restrict__ logits,
    const int* __restrict__ labels,
    float* __restrict__ seg_buf,   // C * N_BINS floats, pre-zeroed
    int N, int C)
{
    const int lane = threadIdx.x & 63;
    const int wv   = threadIdx.x >> 6;
    const int W    = gridDim.x << 2;       // total wave-slots
    const int n4   = C >> 2;

    int row = blockIdx.x * 4 + wv;
    if (row >= N) return;

    vfloat4 bufA[4], bufB[4];
    load_row(logits, (size_t)row, C, lane, n4, bufA);

    // 2-stage unrolled ping-pong so buffer indices stay compile-time constant.
    for (;;) {
        int next = row + W;
        if (next >= N) { compute_row(bufA, lane, n4, labels, seg_buf, row); break; }
        load_row(logits, (size_t)next, C, lane, n4, bufB);
        compute_row(bufA, lane, n4, labels, seg_buf, row);
        row = next;

        next = row + W;
        if (next >= N) { compute_row(bufB, lane, n4, labels, seg_buf, row); break; }
        load_row(logits, (size_t)next, C, lane, n4, bufA);
        compute_row(bufB, lane, n4, labels, seg_buf, row);
        row = next;
    }
}

// ---- final reduction: ecce = sum(|seg_buf[i]|) / N -------------------------
// Single block (deterministic), 16 waves for memory-level parallelism over
// the 15000-element buffer (~15 loads/thread).
__global__ __launch_bounds__(1024) void ecce_final_kernel(
    const float* __restrict__ seg_buf, float* __restrict__ out,
    int nseg, float invN)
{
    __shared__ float sdata[16];
    float s = 0.0f;
    for (int i = threadIdx.x; i < nseg; i += 1024) s += fabsf(seg_buf[i]);
    #pragma unroll
    for (int off = 32; off >= 1; off >>= 1) s += __shfl_xor(s, off, 64);
    const int lane = threadIdx.x & 63;
    const int wv   = threadIdx.x >> 6;
    if (lane == 0) sdata[wv] = s;
    __syncthreads();
    if (threadIdx.x == 0) {
        float t = 0.0f;
        #pragma unroll
        for (int k = 0; k < 16; ++k) t += sdata[k];
        out[0] = t * invN;
    }
}

extern "C" void kernel_launch(void* const* d_in, const int* in_sizes, int n_in,
                              void* d_out, int out_size, void* d_ws, size_t ws_size,
                              hipStream_t stream) {
    const float* logits = (const float*)d_in[0];
    const int*   labels = (const int*)d_in[1];
    const int N = in_sizes[1];
    const int C = in_sizes[0] / N;
    const int nseg = C * N_BINS;

    float* seg_buf = (float*)d_ws;
    (void)hipMemsetAsync(seg_buf, 0, (size_t)nseg * sizeof(float), stream);

    // 2048 blocks = 256 CUs x 8 blocks; each wave handles N/8192 rows.
    int blocks = (N + 3) / 4;
    if (blocks > 2048) blocks = 2048;
    ecce_rows_kernel<<<blocks, 256, 0, stream>>>(logits, labels, seg_buf, N, C);

    ecce_final_kernel<<<1, 1024, 0, stream>>>(seg_buf, (float*)d_out, nseg, 1.0f / (float)N);
}

// Round 2
// 629.153 us; speedup vs baseline: 1.0521x; 1.0521x over previous
//
#include <hip/hip_runtime.h>
#include <math.h>

#define N_BINS 15

typedef float vfloat4 __attribute__((ext_vector_type(4)));

// One wave (64 lanes) per row; C=1000 -> 250 float4s, 4 per lane (clamped).
// ZERO local arrays / array params anywhere: every value is a named scalar or
// named ext-vector, so nothing can fall into scratch (rule #20). Straight-line.
__global__ __launch_bounds__(256) void ecce_rows_kernel(
    const float* __restrict__ logits,
    const int* __restrict__ labels,
    float* __restrict__ seg_buf,   // C * N_BINS floats, pre-zeroed
    int N, int C)
{
    const int lane = threadIdx.x & 63;
    const int wv   = threadIdx.x >> 6;
    const int row  = blockIdx.x * 4 + wv;
    if (row >= N) return;

    const int n4 = C >> 2;  // float4s per row (C % 4 == 0)
    const vfloat4* __restrict__ rowp =
        (const vfloat4*)(logits + (size_t)row * (size_t)C);

    // Clamped unconditional loads: out-of-range lanes re-read the last float4
    // (same cacheline, no exec divergence); masked to -INF below.
    const int j0 = lane, j1 = lane + 64, j2 = lane + 128, j3 = lane + 192;
    const bool k0 = j0 < n4, k1 = j1 < n4, k2 = j2 < n4, k3 = j3 < n4;
    const vfloat4 a0 = __builtin_nontemporal_load(&rowp[k0 ? j0 : n4 - 1]);
    const vfloat4 a1 = __builtin_nontemporal_load(&rowp[k1 ? j1 : n4 - 1]);
    const vfloat4 a2 = __builtin_nontemporal_load(&rowp[k2 ? j2 : n4 - 1]);
    const vfloat4 a3 = __builtin_nontemporal_load(&rowp[k3 ? j3 : n4 - 1]);
    const int label = labels[row];  // wave-uniform; issue early, used at the end

    const float NI = -INFINITY;
    const float v0  = k0 ? a0.x : NI, v1  = k0 ? a0.y : NI,
                v2  = k0 ? a0.z : NI, v3  = k0 ? a0.w : NI;
    const float v4  = k1 ? a1.x : NI, v5  = k1 ? a1.y : NI,
                v6  = k1 ? a1.z : NI, v7  = k1 ? a1.w : NI;
    const float v8  = k2 ? a2.x : NI, v9  = k2 ? a2.y : NI,
                v10 = k2 ? a2.z : NI, v11 = k2 ? a2.w : NI;
    const float v12 = k3 ? a3.x : NI, v13 = k3 ? a3.y : NI,
                v14 = k3 ? a3.z : NI, v15 = k3 ? a3.w : NI;

    // Lane-local max (same order as before).
    float m = v0;
    m = fmaxf(m, v1);  m = fmaxf(m, v2);  m = fmaxf(m, v3);
    m = fmaxf(m, v4);  m = fmaxf(m, v5);  m = fmaxf(m, v6);  m = fmaxf(m, v7);
    m = fmaxf(m, v8);  m = fmaxf(m, v9);  m = fmaxf(m, v10); m = fmaxf(m, v11);
    m = fmaxf(m, v12); m = fmaxf(m, v13); m = fmaxf(m, v14); m = fmaxf(m, v15);

    // Lane-local first-occurrence argmax: descending scan, overwrite on match
    // == min index among elements equal to the lane max. Element index
    // (= class id) of v_k is 4*j_g + e. -INF fillers never match finite m.
    int cand = 0x7fffffff;
    cand = (v15 == m) ? 4*j3+3 : cand;  cand = (v14 == m) ? 4*j3+2 : cand;
    cand = (v13 == m) ? 4*j3+1 : cand;  cand = (v12 == m) ? 4*j3+0 : cand;
    cand = (v11 == m) ? 4*j2+3 : cand;  cand = (v10 == m) ? 4*j2+2 : cand;
    cand = (v9  == m) ? 4*j2+1 : cand;  cand = (v8  == m) ? 4*j2+0 : cand;
    cand = (v7  == m) ? 4*j1+3 : cand;  cand = (v6  == m) ? 4*j1+2 : cand;
    cand = (v5  == m) ? 4*j1+1 : cand;  cand = (v4  == m) ? 4*j1+0 : cand;
    cand = (v3  == m) ? 4*j0+3 : cand;  cand = (v2  == m) ? 4*j0+2 : cand;
    cand = (v1  == m) ? 4*j0+1 : cand;  cand = (v0  == m) ? 4*j0+0 : cand;

    // Fused (max, argmax) butterfly: 6 rounds. Hierarchical
    // min-index-among-maxima == global first-occurrence argmax.
    #pragma unroll
    for (int off = 32; off >= 1; off >>= 1) {
        const float mo = __shfl_xor(m, off, 64);
        const int   co = __shfl_xor(cand, off, 64);
        const bool take = (mo > m);
        const bool tie  = (mo == m);
        const int  cmin = (co < cand) ? co : cand;
        cand = take ? co : (tie ? cmin : cand);
        m    = fmaxf(m, mo);
    }

    // Softmax denominator: identical accumulation order to previous kernels.
    float s = 0.0f;
    s += __expf(v0 - m);  s += __expf(v1 - m);  s += __expf(v2 - m);  s += __expf(v3 - m);
    s += __expf(v4 - m);  s += __expf(v5 - m);  s += __expf(v6 - m);  s += __expf(v7 - m);
    s += __expf(v8 - m);  s += __expf(v9 - m);  s += __expf(v10 - m); s += __expf(v11 - m);
    s += __expf(v12 - m); s += __expf(v13 - m); s += __expf(v14 - m); s += __expf(v15 - m);
    #pragma unroll
    for (int off = 32; off >= 1; off >>= 1)
        s += __shfl_xor(s, off, 64);

    if (lane == 0) {
        const float conf = 1.0f / s;               // exp(m-m)/sum
        int bin = (int)ceilf(conf * (float)N_BINS) - 1;
        bin = bin < 0 ? 0 : (bin > N_BINS - 1 ? N_BINS - 1 : bin);
        const float acc = (cand == label) ? 1.0f : 0.0f;
        atomicAdd(&seg_buf[label * N_BINS + bin], conf - acc);
    }
}

// Single-block final reduction: ecce = sum(|seg_buf[i]|) / N.
// 16 waves for memory-level parallelism over the 15000-element buffer.
__global__ __launch_bounds__(1024) void ecce_final_kernel(
    const float* __restrict__ seg_buf, float* __restrict__ out,
    int nseg, float invN)
{
    __shared__ float sdata[16];
    float s = 0.0f;
    for (int i = threadIdx.x; i < nseg; i += 1024) s += fabsf(seg_buf[i]);
    #pragma unroll
    for (int off = 32; off >= 1; off >>= 1) s += __shfl_xor(s, off, 64);
    const int lane = threadIdx.x & 63;
    const int wv   = threadIdx.x >> 6;
    if (lane == 0) sdata[wv] = s;
    __syncthreads();
    if (threadIdx.x == 0) {
        float t = 0.0f;
        #pragma unroll
        for (int k = 0; k < 16; ++k) t += sdata[k];
        out[0] = t * invN;
    }
}

extern "C" void kernel_launch(void* const* d_in, const int* in_sizes, int n_in,
                              void* d_out, int out_size, void* d_ws, size_t ws_size,
                              hipStream_t stream) {
    const float* logits = (const float*)d_in[0];
    const int*   labels = (const int*)d_in[1];
    const int N = in_sizes[1];
    const int C = in_sizes[0] / N;
    const int nseg = C * N_BINS;

    float* seg_buf = (float*)d_ws;
    (void)hipMemsetAsync(seg_buf, 0, (size_t)nseg * sizeof(float), stream);

    const int rows_per_block = 4;  // 4 waves x 64 lanes, one row per wave
    dim3 grid((N + rows_per_block - 1) / rows_per_block);
    ecce_rows_kernel<<<grid, 256, 0, stream>>>(logits, labels, seg_buf, N, C);

    ecce_final_kernel<<<1, 1024, 0, stream>>>(seg_buf, (float*)d_out, nseg, 1.0f / (float)N);
}